// Round 8
// baseline (334.721 us; speedup 1.0000x reference)
//
#include <hip/hip_runtime.h>

// VACF via banded-Gram MFMA: G[t] = sum_i X[i][:] . X[i+t][:]  (t=0..99)
// = band of X·X^T (T=10000 rows, K=C=3000 contraction), bf16 MFMA.
//
// Round 8: R7 hit the fp32-VALU structural ceiling (~89us busy vs 39us FMA
// floor; m07 sustained rate makes ~90us the realistic floor). Rewrite on
// matrix cores: per 16-row block bi, every pair (i,i+t), t<=99 falls in
// tile d=0..7 ((15+99)>>4=7). Stage X[i0:i0+128) x 32cols to LDS as bf16
// (RNE), 4 waves x 2 tiles: D_d = A·B_d^T via mfma_f32_16x16x32_bf16.
// D lane map (m89): n=lane&15, m=(lane>>4)*4+reg; lag t=16d+n-m, mask to
// [0,100). Zero-pad rows>=T and K-remainder => edge terms contribute 0.
// K split x4 over blockIdx.y for occupancy. bf16 precision: mean-error
// ~3e-7 << 2e-2 threshold (random-sign term errors average out).

#define T_DIM 10000
#define C_DIM 3000
#define W 100
#define NBI 625        // T_DIM / 16 block-rows
#define KSPLIT 4
#define KRANGE 750     // C_DIM / KSPLIT (not mult of 32: last iter zero-padded)
#define ROWS 128       // staged rows per workgroup
#define KB 32          // staged cols per iteration
#define LPAD 40        // LDS row pitch in bf16 elems (80 B: 20-bank stride, 2-way max)

typedef __attribute__((ext_vector_type(8)))  short  short8;   // 8 bf16 (4 VGPRs)
typedef __attribute__((ext_vector_type(4)))  float  float4v;

__device__ __forceinline__ short f2bf(float f) {   // RNE fp32 -> bf16 (finite inputs)
    unsigned u = __float_as_uint(f);
    u += 0x7fffu + ((u >> 16) & 1u);
    return (short)(u >> 16);
}

__global__ void vacf_mfma(const float* __restrict__ X, float* __restrict__ partial) {
    const int tid  = threadIdx.x;
    const int lane = tid & 63;
    const int wv   = tid >> 6;
    const int i0   = blockIdx.x * 16;          // A-block first row
    const int ks   = blockIdx.y * KRANGE;      // K range [ks, ke)
    const int ke   = ks + KRANGE;

    __shared__ short buf[ROWS * LPAD];         // 10 KB staged bf16 tile
    __shared__ float bins[W];

    if (tid < W) bins[tid] = 0.f;

    // staging role: thread -> (row, 16-col half)
    const int sr  = tid >> 1;                  // 0..127
    const int sh  = (tid & 1) * 16;            // 0 or 16
    const int row = i0 + sr;
    const bool rowok = row < T_DIM;
    const float* srcrow = X + (size_t)row * C_DIM;   // safe: only deref when rowok
    short* dst = &buf[sr * LPAD + sh];

    // MFMA fragment addresses (m = lane&15 row for A; +16d rows for B_d)
    const int n    = lane & 15;
    const int quad = lane >> 4;
    const int d0   = wv * 2;
    const short* pa  = &buf[n * LPAD + quad * 8];
    const short* pb0 = pa + 16 * d0 * LPAD;
    const short* pb1 = pa + 16 * (d0 + 1) * LPAD;

    float4v acc0 = {0.f, 0.f, 0.f, 0.f};
    float4v acc1 = {0.f, 0.f, 0.f, 0.f};

    const int nIter = (KRANGE + KB - 1) / KB;  // 24 (last has 14 valid cols)
    #pragma unroll 1
    for (int it = 0; it < nIter; ++it) {
        const int k0 = ks + it * KB;
        const bool kfull = (k0 + KB <= ke);

        if (rowok & kfull) {
            const float* s = srcrow + k0 + sh;
            float4v v0 = *(const float4v*)(s);
            float4v v1 = *(const float4v*)(s + 4);
            float4v v2 = *(const float4v*)(s + 8);
            float4v v3 = *(const float4v*)(s + 12);
            short8 o0, o1;
            #pragma unroll
            for (int i = 0; i < 4; ++i) {
                o0[i]     = f2bf(v0[i]);
                o0[i + 4] = f2bf(v1[i]);
                o1[i]     = f2bf(v2[i]);
                o1[i + 4] = f2bf(v3[i]);
            }
            *(short8*)(dst)     = o0;
            *(short8*)(dst + 8) = o1;
        } else {
            // edge path: per-element guard, zeros elsewhere (exact)
            short tmp[16];
            #pragma unroll
            for (int i = 0; i < 16; ++i) {
                const int c = k0 + sh + i;
                float f = (rowok && c < ke) ? srcrow[c] : 0.f;
                tmp[i] = f2bf(f);
            }
            short8 o0, o1;
            #pragma unroll
            for (int i = 0; i < 8; ++i) { o0[i] = tmp[i]; o1[i] = tmp[i + 8]; }
            *(short8*)(dst)     = o0;
            *(short8*)(dst + 8) = o1;
        }
        __syncthreads();

        short8 a  = *(const short8*)pa;
        short8 b0 = *(const short8*)pb0;
        short8 b1 = *(const short8*)pb1;
        acc0 = __builtin_amdgcn_mfma_f32_16x16x32_bf16(a, b0, acc0, 0, 0, 0);
        acc1 = __builtin_amdgcn_mfma_f32_16x16x32_bf16(a, b1, acc1, 0, 0, 0);
        __syncthreads();
    }

    // epilogue: D[m][n] contributes to lag t = 16d + n - m
    #pragma unroll
    for (int p = 0; p < 4; ++p) {
        const int m  = quad * 4 + p;
        const int t0 = 16 * d0 + n - m;
        if (t0 >= 0 && t0 < W)           atomicAdd(&bins[t0], acc0[p]);
        const int t1 = t0 + 16;
        if (t1 >= 0 && t1 < W)           atomicAdd(&bins[t1], acc1[p]);
    }
    __syncthreads();
    if (tid < W) atomicAdd(&partial[tid], bins[tid]);
}

__global__ void vacf_scale(const float* __restrict__ partial, float* __restrict__ out) {
    int t = threadIdx.x;
    if (t < W) out[t] = partial[t] / ((float)(T_DIM - t) * (float)C_DIM);
}

extern "C" void kernel_launch(void* const* d_in, const int* in_sizes, int n_in,
                              void* d_out, int out_size, void* d_ws, size_t ws_size,
                              hipStream_t stream) {
    const float* X = (const float*)d_in[0];
    float* out = (float*)d_out;
    float* ws  = (float*)d_ws;

    hipMemsetAsync(ws, 0, W * sizeof(float), stream);
    dim3 grid(NBI, KSPLIT);
    vacf_mfma<<<grid, 256, 0, stream>>>(X, ws);
    vacf_scale<<<1, 128, 0, stream>>>(ws, out);
}

// Round 9
// 239.858 us; speedup vs baseline: 1.3955x; 1.3955x over previous
//
#include <hip/hip_runtime.h>

// VACF via banded-Gram MFMA, round 9.
// G[t] = sum_i X[i][:] . X[i+t][:]  (t=0..99), X = [T=10000, C=3000] fp32.
//
// R8 was miss-traffic-bound: FETCH 612MB @ 3TB/s = dur (204us), because the
// 16-row A-block gave only 16 MACs/staged-elem (960MB requests) and XCD
// round-robin killed inter-block L2 reuse; LPAD=40 also caused 6.7e6 LDS
// bank conflicts. Fixes:
//  - MA=112 A-rows/block, 224 staged rows -> 56 MFMAs/k-step, 64 MACs/elem,
//    242MB total requests.
//  - lag t=16d+n-m is a-independent: each wave owns d in {2wv,2wv+1} and
//    sums all 7 a-tiles into TWO float4 accs (8 VGPRs).
//  - swizzle: ks=blockIdx.x&7, bb=blockIdx.x>>3 (per-XCD constant k-slice,
//    consecutive bb share 112/224 rows).
//  - LPAD=34 shorts (17-bank stride, <=2-way b128 = free).
//  - register prefetch of next k-block before the MFMA work.

#define T_DIM 10000
#define C_DIM 3000
#define W 100
#define MA 112          // A rows per block
#define NA 7            // A subblocks of 16
#define SROWS 224       // staged rows (A + 112-row band)
#define NBB 90          // ceil(T_DIM / MA) -> covers 10080 rows (tail zeroed)
#define KSPLIT 8
#define KSL 375         // C_DIM / KSPLIT
#define KB 32           // cols per k-iter
#define NIT 12          // ceil(KSL / KB), last iter zero-padded (375..383)
#define LPAD 34         // LDS row pitch in shorts

typedef __attribute__((ext_vector_type(8))) short short8;    // 8 bf16
typedef __attribute__((ext_vector_type(4))) short short4v;   // 4 bf16
typedef __attribute__((ext_vector_type(4))) float float4v;

__device__ __forceinline__ short f2bf(float f) {   // RNE fp32->bf16 (finite)
    unsigned u = __float_as_uint(f);
    u += 0x7fffu + ((u >> 16) & 1u);
    return (short)(u >> 16);
}

__global__ __launch_bounds__(256, 2)
void vacf_mfma(const float* __restrict__ X, float* __restrict__ partial) {
    const int tid  = threadIdx.x;
    const int lane = tid & 63;
    const int wv   = tid >> 6;
    const int ksix = blockIdx.x & 7;           // k-slice (XCD-constant)
    const int bb   = blockIdx.x >> 3;          // row-block (consecutive on XCD)
    const int i0   = bb * MA;
    const int ks   = ksix * KSL;
    const int ke   = ks + KSL;

    __shared__ short buf[SROWS * LPAD];        // 15.2 KB
    __shared__ float bins[W];
    if (tid < W) bins[tid] = 0.f;

    // staging map: thread -> (row r0 + 32s, cols 4cp..4cp+3), s = 0..6
    const int cp = tid & 7;
    const int r0 = tid >> 3;

    // fragment addressing
    const int n    = lane & 15;
    const int quad = lane >> 4;
    const int d0   = 2 * wv;                   // this wave's d-pair: d0, d0+1
    const short* fragbase = &buf[n * LPAD + quad * 8];

    float4v acc0 = {0.f, 0.f, 0.f, 0.f};
    float4v acc1 = {0.f, 0.f, 0.f, 0.f};
    float4v pf[NA];                            // 7 x float4 prefetch regs

    // prologue: load iteration 0
    {
        const int k0 = ks;
        #pragma unroll
        for (int s = 0; s < NA; ++s) {
            const int row = i0 + r0 + 32 * s;
            const int col = k0 + 4 * cp;
            if (row < T_DIM) {                 // k0==ks: cols always in range
                pf[s] = *(const float4v*)(X + (size_t)row * C_DIM + col);
            } else {
                pf[s] = (float4v){0.f, 0.f, 0.f, 0.f};
            }
        }
    }

    #pragma unroll 1
    for (int it = 0; it < NIT; ++it) {
        __syncthreads();                       // prev ds_reads done (and bins init)

        // convert + stage current block
        #pragma unroll
        for (int s = 0; s < NA; ++s) {
            short4v o;
            o[0] = f2bf(pf[s][0]); o[1] = f2bf(pf[s][1]);
            o[2] = f2bf(pf[s][2]); o[3] = f2bf(pf[s][3]);
            *(short4v*)&buf[(r0 + 32 * s) * LPAD + 4 * cp] = o;
        }
        __syncthreads();                       // staging visible

        // prefetch next iteration (consumed after this iter's MFMA work)
        if (it + 1 < NIT) {
            const int k0 = ks + (it + 1) * KB;
            const bool kfull = (k0 + KB <= ke);
            #pragma unroll
            for (int s = 0; s < NA; ++s) {
                const int row = i0 + r0 + 32 * s;
                const int col = k0 + 4 * cp;
                if ((row < T_DIM) & kfull) {
                    pf[s] = *(const float4v*)(X + (size_t)row * C_DIM + col);
                } else {
                    #pragma unroll
                    for (int e = 0; e < 4; ++e)
                        pf[s][e] = (row < T_DIM && col + e < ke)
                                     ? X[(size_t)row * C_DIM + col + e] : 0.f;
                }
            }
        }

        // fragments: A subblocks 0..6, B subblocks d0..d0+7
        short8 fa[NA], fb[8];
        #pragma unroll
        for (int a = 0; a < NA; ++a)
            fa[a] = *(const short8*)(fragbase + 16 * a * LPAD);
        #pragma unroll
        for (int u = 0; u < 8; ++u)
            fb[u] = *(const short8*)(fragbase + 16 * (d0 + u) * LPAD);

        // 14 MFMAs: acc0 sums tiles (a, d0), acc1 sums tiles (a, d0+1)
        #pragma unroll
        for (int a = 0; a < NA; ++a) {
            acc0 = __builtin_amdgcn_mfma_f32_16x16x32_bf16(fa[a], fb[a],     acc0, 0, 0, 0);
            acc1 = __builtin_amdgcn_mfma_f32_16x16x32_bf16(fa[a], fb[a + 1], acc1, 0, 0, 0);
        }
    }

    // epilogue: D[m][n] of diagonal d -> lag t = 16d + n - m  (m = quad*4 + p)
    #pragma unroll
    for (int p = 0; p < 4; ++p) {
        const int m  = quad * 4 + p;
        const int t0 = 16 * d0 + n - m;
        if (t0 >= 0 && t0 < W) atomicAdd(&bins[t0], acc0[p]);
        const int t1 = t0 + 16;
        if (t1 >= 0 && t1 < W) atomicAdd(&bins[t1], acc1[p]);
    }
    __syncthreads();
    if (tid < W) atomicAdd(&partial[tid], bins[tid]);
}

__global__ void vacf_scale(const float* __restrict__ partial, float* __restrict__ out) {
    int t = threadIdx.x;
    if (t < W) out[t] = partial[t] / ((float)(T_DIM - t) * (float)C_DIM);
}

extern "C" void kernel_launch(void* const* d_in, const int* in_sizes, int n_in,
                              void* d_out, int out_size, void* d_ws, size_t ws_size,
                              hipStream_t stream) {
    const float* X = (const float*)d_in[0];
    float* out = (float*)d_out;
    float* ws  = (float*)d_ws;

    hipMemsetAsync(ws, 0, W * sizeof(float), stream);
    vacf_mfma<<<NBB * KSPLIT, 256, 0, stream>>>(X, ws);
    vacf_scale<<<1, 128, 0, stream>>>(ws, out);
}